// Round 10
// baseline (228.346 us; speedup 1.0000x reference)
//
#include <hip/hip_runtime.h>

#define B_ 2
#define T_ 4096
#define E_ 768
#define H_ 12
#define S_ 64
#define WIN_ 256
#define GX_ 64   // T_/64, for the XCD swizzle

typedef unsigned short u16;
typedef unsigned int u32;
typedef __attribute__((ext_vector_type(8))) short bf16x8;
typedef __attribute__((ext_vector_type(4))) short bf16x4;
typedef __attribute__((ext_vector_type(4))) float f32x4;

__device__ __forceinline__ u16 f2bf(float f) {
  u32 u = __float_as_uint(f);
  u += ((u >> 16) & 1u) + 0x7fffu;   // RNE
  return (u16)(u >> 16);
}

__device__ __forceinline__ u32 cvt_pk_bf16(float lo, float hi) {
  u32 r;
  asm("v_cvt_pk_bf16_f32 %0, %1, %2" : "=v"(r) : "v"(lo), "v"(hi));
  return r;
}

__device__ __forceinline__ void async_copy16(const u16* g, u16* l) {
  __builtin_amdgcn_global_load_lds(
      (const __attribute__((address_space(1))) void*)g,
      (__attribute__((address_space(3))) void*)l, 16, 0, 0);
}

// ---------------- fp32 -> bf16, all 4 tensors in one dispatch ----------------
__global__ void cvt_all(const float* __restrict__ x, const float* __restrict__ wq,
                        const float* __restrict__ wk, const float* __restrict__ wv,
                        u16* __restrict__ xb, u16* __restrict__ wb) {
  const int n4x = B_ * T_ * E_ / 4;
  const int n4w = E_ * E_ / 4;
  int i = blockIdx.x * 256 + threadIdx.x;
  const float* src;
  u16* dst;
  int j;
  if (i < n4x) {
    src = x; dst = xb; j = i;
  } else {
    int t = i - n4x;
    int z = t / n4w;
    if (z >= 3) return;
    j = t - z * n4w;
    src = (z == 0) ? wq : ((z == 1) ? wk : wv);
    dst = wb + (size_t)z * E_ * E_;
  }
  float4 v = ((const float4*)src)[j];
  ushort4 o;
  o.x = f2bf(v.x); o.y = f2bf(v.y); o.z = f2bf(v.z); o.w = f2bf(v.w);
  ((ushort4*)dst)[j] = o;
}

// ---------------- QKV projection GEMM (round-3 structure, unchanged) ----------------
__global__ __launch_bounds__(256)
void gemm_qkv(const u16* __restrict__ xb, const u16* __restrict__ wb,
              u16* __restrict__ qkv) {
  const int M = B_ * T_;
  __shared__ u16 As[3][128][32];   // [buf][row][k]  24KB, 64B rows
  __shared__ u16 Bs[3][128][32];   // 24KB
  int tid = threadIdx.x;
  int lane = tid & 63, wave = tid >> 6;
  int wr = wave >> 1, wc = wave & 1;
  int q8 = lane >> 4, nl = lane & 15;
  int bm = blockIdx.x * 128, bn = blockIdx.y * 128;
  int z = blockIdx.z;
  const u16* A = xb;
  const u16* Bmat = wb + (size_t)z * E_ * E_;
  u16* C = qkv + (size_t)z * M * E_;
  float scale = (z == 0) ? (0.125f * 1.44269504088896f) : 1.0f;

  int r0 = tid >> 2, c0 = tid & 3;
  int cs = c0 ^ (r0 & 3);
  const u16* ga0 = A + (size_t)(bm + r0) * E_ + cs * 8;
  const u16* ga1 = A + (size_t)(bm + r0 + 64) * E_ + cs * 8;
  const u16* gb0 = Bmat + (size_t)(bn + r0) * E_ + cs * 8;
  const u16* gb1 = Bmat + (size_t)(bn + r0 + 64) * E_ + cs * 8;
  int l0 = tid * 8;          // u16 offset of slot t
  int l1 = tid * 8 + 2048;   // slot t+256

  int swz8 = (q8 ^ (nl & 3)) * 8;

  const int NK = E_ / 32;   // 24, divisible by 3
#pragma unroll
  for (int p = 0; p < 2; ++p) {
    int koff = p * 32;
    async_copy16(ga0 + koff, &As[p][0][0] + l0);
    async_copy16(ga1 + koff, &As[p][0][0] + l1);
    async_copy16(gb0 + koff, &Bs[p][0][0] + l0);
    async_copy16(gb1 + koff, &Bs[p][0][0] + l1);
  }

  f32x4 acc[4][4] = {};

#define KSTEP(KI, BUF, PBUF)                                                   \
  {                                                                            \
    asm volatile("s_waitcnt vmcnt(4) lgkmcnt(0)" ::: "memory");                \
    __builtin_amdgcn_s_barrier();                                              \
    __builtin_amdgcn_sched_barrier(0);                                         \
    int kp = ((KI) + 2 < NK) ? (KI) + 2 : NK - 1;                              \
    int koff = kp * 32;                                                        \
    async_copy16(ga0 + koff, &As[PBUF][0][0] + l0);                            \
    async_copy16(ga1 + koff, &As[PBUF][0][0] + l1);                            \
    async_copy16(gb0 + koff, &Bs[PBUF][0][0] + l0);                            \
    async_copy16(gb1 + koff, &Bs[PBUF][0][0] + l1);                            \
    bf16x8 af[4], bfr[4];                                                      \
    _Pragma("unroll")                                                          \
    for (int i = 0; i < 4; ++i)                                                \
      af[i] = *(const bf16x8*)&As[BUF][wr * 64 + i * 16 + nl][swz8];           \
    _Pragma("unroll")                                                          \
    for (int i = 0; i < 4; ++i)                                                \
      bfr[i] = *(const bf16x8*)&Bs[BUF][wc * 64 + i * 16 + nl][swz8];          \
    __builtin_amdgcn_s_setprio(1);                                             \
    _Pragma("unroll")                                                          \
    for (int i = 0; i < 4; ++i)                                                \
      _Pragma("unroll")                                                        \
      for (int j2 = 0; j2 < 4; ++j2)                                           \
        acc[i][j2] = __builtin_amdgcn_mfma_f32_16x16x32_bf16(af[i], bfr[j2],   \
                                                             acc[i][j2], 0, 0, 0); \
    __builtin_amdgcn_s_setprio(0);                                             \
  }

  for (int kb = 0; kb < NK; kb += 3) {
    KSTEP(kb + 0, 0, 2)
    KSTEP(kb + 1, 1, 0)
    KSTEP(kb + 2, 2, 1)
  }
#undef KSTEP

#pragma unroll
  for (int i = 0; i < 4; ++i)
#pragma unroll
    for (int j2 = 0; j2 < 4; ++j2)
#pragma unroll
      for (int r = 0; r < 4; ++r) {
        int row = bm + wr * 64 + i * 16 + q8 * 4 + r;
        int col = bn + wc * 64 + j2 * 16 + nl;
        C[(size_t)row * E_ + col] = f2bf(acc[i][j2][r] * scale);
      }
}

// ---------------- V transpose: v[b*T+t][e] -> vT[b][e][t] ----------------
__global__ void transpose_v(const u16* __restrict__ v, u16* __restrict__ vT) {
  __shared__ u16 lt[64][66];
  int t = threadIdx.x;
  int t0 = blockIdx.x * 64;
  int e0 = blockIdx.y * 64;
  int b = blockIdx.z;
#pragma unroll
  for (int i = 0; i < 2; ++i) {
    int u = t + i * 256;
    int tok = u >> 3, cg = u & 7;
    bf16x8 val = *(const bf16x8*)(v + (size_t)(b * T_ + t0 + tok) * E_ + e0 + cg * 8);
#pragma unroll
    for (int j = 0; j < 8; ++j) lt[tok][cg * 8 + j] = (u16)val[j];
  }
  __syncthreads();
#pragma unroll
  for (int i = 0; i < 2; ++i) {
    int u = t + i * 256;
    int d = u >> 3, ck = u & 7;
    bf16x8 o;
#pragma unroll
    for (int j = 0; j < 8; ++j) o[j] = (short)lt[ck * 8 + j][d];
    *(bf16x8*)(vT + (size_t)(b * E_ + e0 + d) * T_ + t0 + ck * 8) = o;
  }
}

// ---------------- banded flash attention: 16 queries/wave, 32-aligned K tiles ----------------
// Round-9 bug: odd waves (qw=16 mod 32) had klo=16 mod 32, so when khi clamped
// to T the last tile read 16 keys PAST the sequence end, unmasked (they looked
// band-interior). Fix: align klo down to 32 (klo &= ~31) -> every tile is
// 32-aligned, last tile ends at T-1, all reads in-bounds. The extra edge keys
// this adds (d in [-272,-257] front, [257,287] back) violate the band and are
// caught by the existing elementwise mask; both edge tiles fire the
// wave-uniform trigger (kt < qw-241 / kt > qw+225). Verified case-by-case.
// Structure: 16 q-rows/wave -> 1536 blocks = 24 waves/CU ceiling (2x round-8).
// K/V duplication is XCD-L2-local (bijective swizzle, 1536 = 8 x 192).
// NOTE: never pass a second __launch_bounds__ arg (rounds 6/7 spilled).
__global__ __launch_bounds__(256)
void attn_kernel(const u16* __restrict__ qkv, const u16* __restrict__ vT,
                 float* __restrict__ out) {
  const int Mtot = B_ * T_;
  const u16* qb = qkv;
  const u16* kb = qkv + (size_t)Mtot * E_;

  int tid = threadIdx.x;
  int lane = tid & 63, wave = tid >> 6;
  int q8 = lane >> 4, nl = lane & 15;

  // bijective XCD swizzle: d = by*GX+bx; xcd = d&7; 8 consecutive 64-q blocks
  // of the same (b,h) land on one XCD.
  int d = blockIdx.y * GX_ + blockIdx.x;
  int xcd = d & 7, jj = d >> 3;
  int nx = xcd * 8 + (jj & 7);
  int ny = jj >> 3;
  int qs = nx * 64;
  int b = ny / H_, h = ny % H_;
  int qw = qs + wave * 16;     // this wave's 16 query rows
  size_t ho = (size_t)h * S_;

  // Q fragment (one 16-row tile, two 32-dim halves)
  bf16x8 aq[2];
  {
    const u16* qrow = qb + (size_t)(b * T_ + qw + nl) * E_ + ho;
    aq[0] = *(const bf16x8*)(qrow + q8 * 8);
    aq[1] = *(const bf16x8*)(qrow + 32 + q8 * 8);
  }

  f32x4 O[4] = {};
  float lacc = 0.f;

  int klo = qw - WIN_; if (klo < 0) klo = 0;
  klo &= ~31;   // 32-align tiles: last tile never crosses T (round-9 fix)
  int khi = qw + 16 + WIN_; if (khi > T_) khi = T_;

  const u16* kbase = kb + (size_t)b * T_ * E_ + ho;
  const u16* vbase = vT + (size_t)b * E_ * T_ + ho * T_;

  // bpermute lane addresses for the P k-quad redistribution
  int alo = ((((q8 << 1) & 3) << 4) + nl) << 2;
  int ahi = alo + 64;
  bool hint = q8 >= 2;

  // prefetch first K tile
  bf16x8 bk[2][2];
#pragma unroll
  for (int nt = 0; nt < 2; ++nt) {
    const u16* krow = kbase + (size_t)(klo + nt * 16 + nl) * E_;
    bk[nt][0] = *(const bf16x8*)(krow + q8 * 8);
    bk[nt][1] = *(const bf16x8*)(krow + 32 + q8 * 8);
  }

  for (int kt = klo; kt < khi; kt += 32) {
    // ---- V loads for THIS round issued early ----
    bf16x8 bv[4];
#pragma unroll
    for (int dt = 0; dt < 4; ++dt)
      bv[dt] = *(const bf16x8*)(vbase + (size_t)(dt * 16 + nl) * T_ + kt + q8 * 8);

    // ---- K prefetch for NEXT round (clamped) ----
    int ktn = (kt + 32 < khi) ? kt + 32 : kt;
    bf16x8 nbk[2][2];
#pragma unroll
    for (int nt = 0; nt < 2; ++nt) {
      const u16* krow = kbase + (size_t)(ktn + nt * 16 + nl) * E_;
      nbk[nt][0] = *(const bf16x8*)(krow + q8 * 8);
      nbk[nt][1] = *(const bf16x8*)(krow + 32 + q8 * 8);
    }

    // ---- K^T Q (swapped): lane holds 8 keys for one query q = qw+nl ----
    f32x4 sc[2] = {};
    __builtin_amdgcn_s_setprio(1);
#pragma unroll
    for (int nt = 0; nt < 2; ++nt) {
      sc[nt] = __builtin_amdgcn_mfma_f32_16x16x32_bf16(bk[nt][0], aq[0], sc[nt], 0, 0, 0);
      sc[nt] = __builtin_amdgcn_mfma_f32_16x16x32_bf16(bk[nt][1], aq[1], sc[nt], 0, 0, 0);
    }
    __builtin_amdgcn_s_setprio(0);

    // ---- band mask on edge tiles only (wave-uniform branch) ----
    // 16-row tile: mask needed iff kt < qw-241 or kt > qw+225
    if (kt < qw - 241 || kt > qw + 225) {
#pragma unroll
      for (int nt = 0; nt < 2; ++nt)
#pragma unroll
        for (int r = 0; r < 4; ++r) {
          int qa = qw + nl;
          int ka = kt + nt * 16 + q8 * 4 + r;
          int dd = ka - qa;
          sc[nt][r] = (dd < -WIN_ || dd > WIN_) ? -1e30f : sc[nt][r];
        }
    }

    // ---- fixed-shift softmax, per-lane partial l (one q per lane) ----
    {
      float s = 0.f;
#pragma unroll
      for (int nt = 0; nt < 2; ++nt)
#pragma unroll
        for (int r = 0; r < 4; ++r) {
          float p = exp2f(sc[nt][r]);
          sc[nt][r] = p;
          s += p;
        }
      lacc += s;
    }

    // ---- P -> A-fragment: cvt_pk + ds_bpermute (no LDS storage) ----
    bf16x8 ap;
    {
      u32 pk00 = cvt_pk_bf16(sc[0][0], sc[0][1]);
      u32 pk01 = cvt_pk_bf16(sc[0][2], sc[0][3]);
      u32 pk10 = cvt_pk_bf16(sc[1][0], sc[1][1]);
      u32 pk11 = cvt_pk_bf16(sc[1][2], sc[1][3]);
      int q0a = __builtin_amdgcn_ds_bpermute(alo, (int)pk00);
      int q0b = __builtin_amdgcn_ds_bpermute(alo, (int)pk10);
      int q1a = __builtin_amdgcn_ds_bpermute(alo, (int)pk01);
      int q1b = __builtin_amdgcn_ds_bpermute(alo, (int)pk11);
      int q2a = __builtin_amdgcn_ds_bpermute(ahi, (int)pk00);
      int q2b = __builtin_amdgcn_ds_bpermute(ahi, (int)pk10);
      int q3a = __builtin_amdgcn_ds_bpermute(ahi, (int)pk01);
      int q3b = __builtin_amdgcn_ds_bpermute(ahi, (int)pk11);
      union { u32 w[4]; bf16x8 v; } u;
      u.w[0] = (u32)(hint ? q0b : q0a);
      u.w[1] = (u32)(hint ? q1b : q1a);
      u.w[2] = (u32)(hint ? q2b : q2a);
      u.w[3] = (u32)(hint ? q3b : q3a);
      ap = u.v;
    }

    // ---- P @ V ----
    __builtin_amdgcn_s_setprio(1);
#pragma unroll
    for (int dt = 0; dt < 4; ++dt)
      O[dt] = __builtin_amdgcn_mfma_f32_16x16x32_bf16(ap, bv[dt], O[dt], 0, 0, 0);
    __builtin_amdgcn_s_setprio(0);

    // rotate prefetch
#pragma unroll
    for (int nt = 0; nt < 2; ++nt) {
      bk[nt][0] = nbk[nt][0];
      bk[nt][1] = nbk[nt][1];
    }
  }

  // ---- l reduction across the 4 lane-groups (each lane: full l for q=qw+nl) ----
  lacc += __shfl_xor(lacc, 16);
  lacc += __shfl_xor(lacc, 32);

  // ---- normalize + store (O rows live at q=q8*4+r; pull l from lane nl'=q) ----
#pragma unroll
  for (int r = 0; r < 4; ++r) {
    float lq = __shfl(lacc, (lane & 48) | (q8 * 4 + r));
    float inv = 1.0f / lq;
    int qa = qw + q8 * 4 + r;
    float* op = out + (size_t)(b * T_ + qa) * E_ + ho;
#pragma unroll
    for (int dt = 0; dt < 4; ++dt)
      op[dt * 16 + nl] = O[dt][r] * inv;
  }
}

extern "C" void kernel_launch(void* const* d_in, const int* in_sizes, int n_in,
                              void* d_out, int out_size, void* d_ws, size_t ws_size,
                              hipStream_t stream) {
  const float* x  = (const float*)d_in[0];
  const float* Wq = (const float*)d_in[1];
  const float* Wk = (const float*)d_in[2];
  const float* Wv = (const float*)d_in[3];
  float* out = (float*)d_out;

  const size_t M = (size_t)B_ * T_;
  u16* xb  = (u16*)d_ws;               // M*E bf16; reused as vT after gemm
  u16* wb  = xb + M * E_;              // 3*E*E
  u16* qkv = wb + 3 * (size_t)E_ * E_; // 3*M*E
  u16* vT  = xb;                       // [B][E][T]

  const int n4x = B_ * T_ * E_ / 4;
  const int n4w = E_ * E_ / 4;
  int cvt_blocks = (n4x + 3 * n4w + 255) / 256;
  cvt_all<<<cvt_blocks, 256, 0, stream>>>(x, Wq, Wk, Wv, xb, wb);

  dim3 g1(M / 128, E_ / 128, 3);
  gemm_qkv<<<g1, 256, 0, stream>>>(xb, wb, qkv);

  dim3 gt(T_ / 64, E_ / 64, B_);
  transpose_v<<<gt, 256, 0, stream>>>(qkv + 2 * M * E_, vT);

  dim3 g2(GX_, B_ * H_);
  attn_kernel<<<g2, 256, 0, stream>>>(qkv, vT, out);
}

// Round 11
// 176.642 us; speedup vs baseline: 1.2927x; 1.2927x over previous
//
#include <hip/hip_runtime.h>

#define B_ 2
#define T_ 4096
#define E_ 768
#define H_ 12
#define S_ 64
#define WIN_ 256
#define GX_ 32    // T_/128, for the XCD swizzle
#define TP_ 4128  // padded vT row stride (T_+32): breaks 8KB power-of-2 L1-set aliasing

typedef unsigned short u16;
typedef unsigned int u32;
typedef __attribute__((ext_vector_type(8))) short bf16x8;
typedef __attribute__((ext_vector_type(4))) short bf16x4;
typedef __attribute__((ext_vector_type(4))) float f32x4;

__device__ __forceinline__ u16 f2bf(float f) {
  u32 u = __float_as_uint(f);
  u += ((u >> 16) & 1u) + 0x7fffu;   // RNE
  return (u16)(u >> 16);
}

__device__ __forceinline__ u32 cvt_pk_bf16(float lo, float hi) {
  u32 r;
  asm("v_cvt_pk_bf16_f32 %0, %1, %2" : "=v"(r) : "v"(lo), "v"(hi));
  return r;
}

__device__ __forceinline__ void async_copy16(const u16* g, u16* l) {
  __builtin_amdgcn_global_load_lds(
      (const __attribute__((address_space(1))) void*)g,
      (__attribute__((address_space(3))) void*)l, 16, 0, 0);
}

// ---------------- fp32 -> bf16, all 4 tensors in one dispatch ----------------
__global__ void cvt_all(const float* __restrict__ x, const float* __restrict__ wq,
                        const float* __restrict__ wk, const float* __restrict__ wv,
                        u16* __restrict__ xb, u16* __restrict__ wb) {
  const int n4x = B_ * T_ * E_ / 4;
  const int n4w = E_ * E_ / 4;
  int i = blockIdx.x * 256 + threadIdx.x;
  const float* src;
  u16* dst;
  int j;
  if (i < n4x) {
    src = x; dst = xb; j = i;
  } else {
    int t = i - n4x;
    int z = t / n4w;
    if (z >= 3) return;
    j = t - z * n4w;
    src = (z == 0) ? wq : ((z == 1) ? wk : wv);
    dst = wb + (size_t)z * E_ * E_;
  }
  float4 v = ((const float4*)src)[j];
  ushort4 o;
  o.x = f2bf(v.x); o.y = f2bf(v.y); o.z = f2bf(v.z); o.w = f2bf(v.w);
  ((ushort4*)dst)[j] = o;
}

// ---------------- QKV projection GEMM (round-3 structure, unchanged) ----------------
__global__ __launch_bounds__(256)
void gemm_qkv(const u16* __restrict__ xb, const u16* __restrict__ wb,
              u16* __restrict__ qkv) {
  const int M = B_ * T_;
  __shared__ u16 As[3][128][32];   // [buf][row][k]  24KB, 64B rows
  __shared__ u16 Bs[3][128][32];   // 24KB
  int tid = threadIdx.x;
  int lane = tid & 63, wave = tid >> 6;
  int wr = wave >> 1, wc = wave & 1;
  int q8 = lane >> 4, nl = lane & 15;
  int bm = blockIdx.x * 128, bn = blockIdx.y * 128;
  int z = blockIdx.z;
  const u16* A = xb;
  const u16* Bmat = wb + (size_t)z * E_ * E_;
  u16* C = qkv + (size_t)z * M * E_;
  float scale = (z == 0) ? (0.125f * 1.44269504088896f) : 1.0f;

  int r0 = tid >> 2, c0 = tid & 3;
  int cs = c0 ^ (r0 & 3);
  const u16* ga0 = A + (size_t)(bm + r0) * E_ + cs * 8;
  const u16* ga1 = A + (size_t)(bm + r0 + 64) * E_ + cs * 8;
  const u16* gb0 = Bmat + (size_t)(bn + r0) * E_ + cs * 8;
  const u16* gb1 = Bmat + (size_t)(bn + r0 + 64) * E_ + cs * 8;
  int l0 = tid * 8;          // u16 offset of slot t
  int l1 = tid * 8 + 2048;   // slot t+256

  int swz8 = (q8 ^ (nl & 3)) * 8;

  const int NK = E_ / 32;   // 24, divisible by 3
#pragma unroll
  for (int p = 0; p < 2; ++p) {
    int koff = p * 32;
    async_copy16(ga0 + koff, &As[p][0][0] + l0);
    async_copy16(ga1 + koff, &As[p][0][0] + l1);
    async_copy16(gb0 + koff, &Bs[p][0][0] + l0);
    async_copy16(gb1 + koff, &Bs[p][0][0] + l1);
  }

  f32x4 acc[4][4] = {};

#define KSTEP(KI, BUF, PBUF)                                                   \
  {                                                                            \
    asm volatile("s_waitcnt vmcnt(4) lgkmcnt(0)" ::: "memory");                \
    __builtin_amdgcn_s_barrier();                                              \
    __builtin_amdgcn_sched_barrier(0);                                         \
    int kp = ((KI) + 2 < NK) ? (KI) + 2 : NK - 1;                              \
    int koff = kp * 32;                                                        \
    async_copy16(ga0 + koff, &As[PBUF][0][0] + l0);                            \
    async_copy16(ga1 + koff, &As[PBUF][0][0] + l1);                            \
    async_copy16(gb0 + koff, &Bs[PBUF][0][0] + l0);                            \
    async_copy16(gb1 + koff, &Bs[PBUF][0][0] + l1);                            \
    bf16x8 af[4], bfr[4];                                                      \
    _Pragma("unroll")                                                          \
    for (int i = 0; i < 4; ++i)                                                \
      af[i] = *(const bf16x8*)&As[BUF][wr * 64 + i * 16 + nl][swz8];           \
    _Pragma("unroll")                                                          \
    for (int i = 0; i < 4; ++i)                                                \
      bfr[i] = *(const bf16x8*)&Bs[BUF][wc * 64 + i * 16 + nl][swz8];          \
    __builtin_amdgcn_s_setprio(1);                                             \
    _Pragma("unroll")                                                          \
    for (int i = 0; i < 4; ++i)                                                \
      _Pragma("unroll")                                                        \
      for (int j2 = 0; j2 < 4; ++j2)                                           \
        acc[i][j2] = __builtin_amdgcn_mfma_f32_16x16x32_bf16(af[i], bfr[j2],   \
                                                             acc[i][j2], 0, 0, 0); \
    __builtin_amdgcn_s_setprio(0);                                             \
  }

  for (int kb = 0; kb < NK; kb += 3) {
    KSTEP(kb + 0, 0, 2)
    KSTEP(kb + 1, 1, 0)
    KSTEP(kb + 2, 2, 1)
  }
#undef KSTEP

#pragma unroll
  for (int i = 0; i < 4; ++i)
#pragma unroll
    for (int j2 = 0; j2 < 4; ++j2)
#pragma unroll
      for (int r = 0; r < 4; ++r) {
        int row = bm + wr * 64 + i * 16 + q8 * 4 + r;
        int col = bn + wc * 64 + j2 * 16 + nl;
        C[(size_t)row * E_ + col] = f2bf(acc[i][j2][r] * scale);
      }
}

// ---------------- V transpose: v[b*T+t][e] -> vT[b][e][t], PADDED row stride ----------------
__global__ void transpose_v(const u16* __restrict__ v, u16* __restrict__ vT) {
  __shared__ u16 lt[64][66];
  int t = threadIdx.x;
  int t0 = blockIdx.x * 64;
  int e0 = blockIdx.y * 64;
  int b = blockIdx.z;
#pragma unroll
  for (int i = 0; i < 2; ++i) {
    int u = t + i * 256;
    int tok = u >> 3, cg = u & 7;
    bf16x8 val = *(const bf16x8*)(v + (size_t)(b * T_ + t0 + tok) * E_ + e0 + cg * 8);
#pragma unroll
    for (int j = 0; j < 8; ++j) lt[tok][cg * 8 + j] = (u16)val[j];
  }
  __syncthreads();
#pragma unroll
  for (int i = 0; i < 2; ++i) {
    int u = t + i * 256;
    int d = u >> 3, ck = u & 7;
    bf16x8 o;
#pragma unroll
    for (int j = 0; j < 8; ++j) o[j] = (short)lt[ck * 8 + j][d];
    *(bf16x8*)(vT + (size_t)(b * E_ + e0 + d) * TP_ + t0 + ck * 8) = o;
  }
}

// ---------------- banded flash attention: round-8 structure + padded-V stride ----------------
// Round-10 showed cost tracks V/K load volume (2x loads -> +73% time, all
// utilizations DOWN). Diagnosis: vT rows at stride 8192B = 128 lines = 0 mod
// 64 L1 sets -> every V load's 16 lanes hit ONE L1 set (and one L2 channel
// group) -> permanent conflict-miss thrash on half the loop's loads. Fix:
// vT row stride padded to TP=4128 elements (8256B = 129 lines -> set index
// steps by 1 per row; 16 rows = 16 distinct sets). Attn structure is the
// known-good round-8 kernel (32q/wave, XCD swizzle, in-register P, VGPR 72).
// NOTE: never pass a second __launch_bounds__ arg (rounds 6/7 spilled).
__global__ __launch_bounds__(256)
void attn_kernel(const u16* __restrict__ qkv, const u16* __restrict__ vT,
                 float* __restrict__ out) {
  const int Mtot = B_ * T_;
  const u16* qb = qkv;
  const u16* kb = qkv + (size_t)Mtot * E_;

  int tid = threadIdx.x;
  int lane = tid & 63, wave = tid >> 6;
  int q8 = lane >> 4, nl = lane & 15;

  // bijective XCD swizzle: d = by*GX+bx; xcd = d&7; 4 consecutive q-blocks
  // of the same (b,h) land on one XCD.
  int d = blockIdx.y * GX_ + blockIdx.x;
  int xcd = d & 7, jj = d >> 3;
  int nx = xcd * 4 + (jj & 3);
  int ny = jj >> 2;
  int qs = nx * 128;
  int b = ny / H_, h = ny % H_;
  int qw = qs + wave * 32;
  size_t ho = (size_t)h * S_;

  bf16x8 aq[2][2];
#pragma unroll
  for (int mt = 0; mt < 2; ++mt) {
    const u16* qrow = qb + (size_t)(b * T_ + qw + mt * 16 + nl) * E_ + ho;
    aq[mt][0] = *(const bf16x8*)(qrow + q8 * 8);
    aq[mt][1] = *(const bf16x8*)(qrow + 32 + q8 * 8);
  }

  f32x4 O[2][4] = {};
  float lacc[2] = {0.f, 0.f};

  int klo = qw - WIN_; if (klo < 0) klo = 0;
  int khi = qw + 32 + WIN_; if (khi > T_) khi = T_;

  const u16* kbase = kb + (size_t)b * T_ * E_ + ho;
  const u16* vbase = vT + ((size_t)b * E_ + ho) * TP_;

  // bpermute lane addresses for the P k-quad redistribution
  int alo = ((((q8 << 1) & 3) << 4) + nl) << 2;
  int ahi = alo + 64;
  bool hint = q8 >= 2;

  // prefetch first K tile
  bf16x8 bk[2][2];
#pragma unroll
  for (int nt = 0; nt < 2; ++nt) {
    const u16* krow = kbase + (size_t)(klo + nt * 16 + nl) * E_;
    bk[nt][0] = *(const bf16x8*)(krow + q8 * 8);
    bk[nt][1] = *(const bf16x8*)(krow + 32 + q8 * 8);
  }

  for (int kt = klo; kt < khi; kt += 32) {
    // ---- V loads for THIS round issued early ----
    bf16x8 bv[4];
#pragma unroll
    for (int dt = 0; dt < 4; ++dt)
      bv[dt] = *(const bf16x8*)(vbase + (size_t)(dt * 16 + nl) * TP_ + kt + q8 * 8);

    // ---- K prefetch for NEXT round (clamped) ----
    int ktn = (kt + 32 < khi) ? kt + 32 : kt;
    bf16x8 nbk[2][2];
#pragma unroll
    for (int nt = 0; nt < 2; ++nt) {
      const u16* krow = kbase + (size_t)(ktn + nt * 16 + nl) * E_;
      nbk[nt][0] = *(const bf16x8*)(krow + q8 * 8);
      nbk[nt][1] = *(const bf16x8*)(krow + 32 + q8 * 8);
    }

    // ---- K^T Q (swapped): lane holds 8 keys for one query q=nl ----
    f32x4 sc[2][2] = {};
    __builtin_amdgcn_s_setprio(1);
#pragma unroll
    for (int nt = 0; nt < 2; ++nt)
#pragma unroll
      for (int mt = 0; mt < 2; ++mt) {
        sc[mt][nt] = __builtin_amdgcn_mfma_f32_16x16x32_bf16(bk[nt][0], aq[mt][0], sc[mt][nt], 0, 0, 0);
        sc[mt][nt] = __builtin_amdgcn_mfma_f32_16x16x32_bf16(bk[nt][1], aq[mt][1], sc[mt][nt], 0, 0, 0);
      }
    __builtin_amdgcn_s_setprio(0);

    // ---- band mask on edge tiles only (wave-uniform branch) ----
    if (kt < qw - 225 || kt > qw + 225) {
#pragma unroll
      for (int mt = 0; mt < 2; ++mt)
#pragma unroll
        for (int nt = 0; nt < 2; ++nt)
#pragma unroll
          for (int r = 0; r < 4; ++r) {
            int qa = qw + mt * 16 + nl;
            int ka = kt + nt * 16 + q8 * 4 + r;
            int dd = ka - qa;
            sc[mt][nt][r] = (dd < -WIN_ || dd > WIN_) ? -1e30f : sc[mt][nt][r];
          }
    }

    // ---- fixed-shift softmax, per-lane partial l (one q per lane) ----
#pragma unroll
    for (int mt = 0; mt < 2; ++mt) {
      float s = 0.f;
#pragma unroll
      for (int nt = 0; nt < 2; ++nt)
#pragma unroll
        for (int r = 0; r < 4; ++r) {
          float p = exp2f(sc[mt][nt][r]);
          sc[mt][nt][r] = p;
          s += p;
        }
      lacc[mt] += s;
    }

    // ---- P -> A-fragment: cvt_pk + ds_bpermute (no LDS storage) ----
    bf16x8 ap[2];
#pragma unroll
    for (int mt = 0; mt < 2; ++mt) {
      u32 pk00 = cvt_pk_bf16(sc[mt][0][0], sc[mt][0][1]);
      u32 pk01 = cvt_pk_bf16(sc[mt][0][2], sc[mt][0][3]);
      u32 pk10 = cvt_pk_bf16(sc[mt][1][0], sc[mt][1][1]);
      u32 pk11 = cvt_pk_bf16(sc[mt][1][2], sc[mt][1][3]);
      int q0a = __builtin_amdgcn_ds_bpermute(alo, (int)pk00);
      int q0b = __builtin_amdgcn_ds_bpermute(alo, (int)pk10);
      int q1a = __builtin_amdgcn_ds_bpermute(alo, (int)pk01);
      int q1b = __builtin_amdgcn_ds_bpermute(alo, (int)pk11);
      int q2a = __builtin_amdgcn_ds_bpermute(ahi, (int)pk00);
      int q2b = __builtin_amdgcn_ds_bpermute(ahi, (int)pk10);
      int q3a = __builtin_amdgcn_ds_bpermute(ahi, (int)pk01);
      int q3b = __builtin_amdgcn_ds_bpermute(ahi, (int)pk11);
      union { u32 w[4]; bf16x8 v; } u;
      u.w[0] = (u32)(hint ? q0b : q0a);
      u.w[1] = (u32)(hint ? q1b : q1a);
      u.w[2] = (u32)(hint ? q2b : q2a);
      u.w[3] = (u32)(hint ? q3b : q3a);
      ap[mt] = u.v;
    }

    // ---- P @ V ----
    __builtin_amdgcn_s_setprio(1);
#pragma unroll
    for (int dt = 0; dt < 4; ++dt)
#pragma unroll
      for (int mt = 0; mt < 2; ++mt)
        O[mt][dt] = __builtin_amdgcn_mfma_f32_16x16x32_bf16(ap[mt], bv[dt], O[mt][dt], 0, 0, 0);
    __builtin_amdgcn_s_setprio(0);

    // rotate prefetch
#pragma unroll
    for (int nt = 0; nt < 2; ++nt) {
      bk[nt][0] = nbk[nt][0];
      bk[nt][1] = nbk[nt][1];
    }
  }

  // ---- l reduction across the 4 lane-groups (each lane: full l for q=nl) ----
#pragma unroll
  for (int mt = 0; mt < 2; ++mt) {
    lacc[mt] += __shfl_xor(lacc[mt], 16);
    lacc[mt] += __shfl_xor(lacc[mt], 32);
  }

  // ---- normalize + store (O rows live at q=q8*4+r; pull l from lane nl'=q) ----
#pragma unroll
  for (int mt = 0; mt < 2; ++mt)
#pragma unroll
    for (int r = 0; r < 4; ++r) {
      float lq = __shfl(lacc[mt], (lane & 48) | (q8 * 4 + r));
      float inv = 1.0f / lq;
      int qa = qw + mt * 16 + q8 * 4 + r;
      float* op = out + (size_t)(b * T_ + qa) * E_ + ho;
#pragma unroll
      for (int dt = 0; dt < 4; ++dt)
        op[dt * 16 + nl] = O[mt][dt][r] * inv;
    }
}

extern "C" void kernel_launch(void* const* d_in, const int* in_sizes, int n_in,
                              void* d_out, int out_size, void* d_ws, size_t ws_size,
                              hipStream_t stream) {
  const float* x  = (const float*)d_in[0];
  const float* Wq = (const float*)d_in[1];
  const float* Wk = (const float*)d_in[2];
  const float* Wv = (const float*)d_in[3];
  float* out = (float*)d_out;

  const size_t M = (size_t)B_ * T_;
  u16* xb  = (u16*)d_ws;               // M*E bf16; region reused as vT after gemm
  u16* wb  = xb + M * E_;              // 3*E*E (dead after gemm; vT may overflow into it)
  u16* qkv = wb + 3 * (size_t)E_ * E_; // 3*M*E
  u16* vT  = xb;                       // [B][E][TP_] padded; needs B*E*TP_ = 12.7MB
                                       // xb(12.6MB)+wb(3.5MB) = 16.1MB -> fits, qkv untouched

  const int n4x = B_ * T_ * E_ / 4;
  const int n4w = E_ * E_ / 4;
  int cvt_blocks = (n4x + 3 * n4w + 255) / 256;
  cvt_all<<<cvt_blocks, 256, 0, stream>>>(x, Wq, Wk, Wv, xb, wb);

  dim3 g1(M / 128, E_ / 128, 3);
  gemm_qkv<<<g1, 256, 0, stream>>>(xb, wb, qkv);

  dim3 gt(T_ / 64, E_ / 64, B_);
  transpose_v<<<gt, 256, 0, stream>>>(qkv + 2 * M * E_, vT);

  dim3 g2(GX_, B_ * H_);
  attn_kernel<<<g2, 256, 0, stream>>>(qkv, vT, out);
}